// Round 1
// baseline (2135.288 us; speedup 1.0000x reference)
//
#include <hip/hip_runtime.h>

#define NNODES 50000
#define NEDGES 800000
#define NGRAPHS 2048

// ---------------- degree / norm ----------------
__global__ void deg_count(const int* __restrict__ dst, int* __restrict__ cnt, int E) {
    int e = blockIdx.x * blockDim.x + threadIdx.x;
    if (e < E) atomicAdd(&cnt[dst[e]], 1);
}

__global__ void compute_dis(const int* __restrict__ cnt, float* __restrict__ dis, int M) {
    int n = blockIdx.x * blockDim.x + threadIdx.x;
    if (n < M) dis[n] = rsqrtf((float)(cnt[n] + 1));  // +1 self-loop
}

__global__ void edge_norm(const int* __restrict__ src, const int* __restrict__ dst,
                          const float* __restrict__ dis, float* __restrict__ nrm, int E) {
    int e = blockIdx.x * blockDim.x + threadIdx.x;
    if (e < E) nrm[e] = dis[src[e]] * dis[dst[e]];
}

// ---------------- tiled f32 GEMM: C[M,N] = A[M,K] @ W[K,N] ----------------
#define BM 64
#define BN 64
#define BK 16
__global__ __launch_bounds__(256) void gemm_tiled(const float* __restrict__ A,
                                                  const float* __restrict__ W,
                                                  float* __restrict__ C,
                                                  int M, int K, int N) {
    __shared__ float As[BK][BM + 1];
    __shared__ float Bs[BK][BN + 1];
    int bm = blockIdx.x * BM;
    int bn = blockIdx.y * BN;
    int tid = threadIdx.x;
    int tr = (tid / 16) * 4;   // 0..60
    int tc = (tid % 16) * 4;   // 0..60
    float acc[4][4] = {};
    for (int k0 = 0; k0 < K; k0 += BK) {
        #pragma unroll
        for (int i = 0; i < 4; ++i) {
            int idx = tid + i * 256;
            int r = idx / BK, k = idx % BK;
            int gr = bm + r, gk = k0 + k;
            float v = 0.f;
            if (gr < M && gk < K) v = A[(size_t)gr * K + gk];
            As[k][r] = v;
        }
        #pragma unroll
        for (int i = 0; i < 4; ++i) {
            int idx = tid + i * 256;
            int k = idx / BN, c = idx % BN;
            int gk = k0 + k, gc = bn + c;
            float v = 0.f;
            if (gk < K && gc < N) v = W[(size_t)gk * N + gc];
            Bs[k][c] = v;
        }
        __syncthreads();
        #pragma unroll
        for (int k = 0; k < BK; ++k) {
            float a[4], b[4];
            #pragma unroll
            for (int i = 0; i < 4; ++i) a[i] = As[k][tr + i];
            #pragma unroll
            for (int j = 0; j < 4; ++j) b[j] = Bs[k][tc + j];
            #pragma unroll
            for (int i = 0; i < 4; ++i)
                #pragma unroll
                for (int j = 0; j < 4; ++j) acc[i][j] += a[i] * b[j];
        }
        __syncthreads();
    }
    #pragma unroll
    for (int i = 0; i < 4; ++i) {
        int gr = bm + tr + i;
        if (gr >= M) continue;
        #pragma unroll
        for (int j = 0; j < 4; ++j) {
            int gc = bn + tc + j;
            if (gc < N) C[(size_t)gr * N + gc] = acc[i][j];
        }
    }
}

// ---------------- edge scatter-add: out[dst] += XW[src] * norm ----------------
// 4 edges per block, 64 lanes per edge (coalesced row access)
__global__ __launch_bounds__(256) void scatter_edges(const float* __restrict__ XW,
                                                     const int* __restrict__ src,
                                                     const int* __restrict__ dst,
                                                     const float* __restrict__ nrm,
                                                     float* __restrict__ out,
                                                     int E, int N) {
    int lane = threadIdx.x & 63;
    int grp  = threadIdx.x >> 6;
    int e = blockIdx.x * 4 + grp;
    if (e >= E) return;
    int s = src[e], d = dst[e];
    float nm = nrm[e];
    const float* xr = XW + (size_t)s * N;
    float* orow = out + (size_t)d * N;
    for (int f = lane; f < N; f += 64) {
        atomicAdd(&orow[f], xr[f] * nm);
    }
}

// ---------------- self-loop + bias + relu: B = relu(B + XW*dis^2 + b) ----------------
__global__ void post_layer(float* __restrict__ B, const float* __restrict__ XW,
                           const float* __restrict__ dis, const float* __restrict__ bias,
                           int M, int N) {
    int idx = blockIdx.x * blockDim.x + threadIdx.x;
    if (idx >= M * N) return;
    int n = idx / N, f = idx % N;
    float di = dis[n];
    float v = B[idx] + XW[idx] * di * di + bias[f];
    B[idx] = fmaxf(v, 0.f);
}

// ---------------- global max pool (h >= 0 post-relu -> int atomicMax valid) ----------------
__global__ void pool_max(const float* __restrict__ h, const int* __restrict__ batch,
                         float* __restrict__ g, int M, int N) {
    int idx = blockIdx.x * blockDim.x + threadIdx.x;
    if (idx >= M * N) return;
    int n = idx / N, f = idx % N;
    float v = h[idx];
    atomicMax((int*)&g[(size_t)batch[n] * N + f], __float_as_int(v));
}

// ---------------- final epilogue: out = relu(fc + bfc) + drug2 ----------------
__global__ void final_ep(const float* __restrict__ fcb, const float* __restrict__ bfc,
                         const float* __restrict__ drug2, float* __restrict__ out,
                         int total, int N) {
    int idx = blockIdx.x * blockDim.x + threadIdx.x;
    if (idx >= total) return;
    int j = idx % N;
    out[idx] = fmaxf(fcb[idx] + bfc[j], 0.f) + drug2[idx];
}

extern "C" void kernel_launch(void* const* d_in, const int* in_sizes, int n_in,
                              void* d_out, int out_size, void* d_ws, size_t ws_size,
                              hipStream_t stream) {
    const float* x     = (const float*)d_in[0];
    const int*   eidx  = (const int*)d_in[1];
    const int*   batch = (const int*)d_in[2];
    const float* drug2 = (const float*)d_in[3];
    const float* W1 = (const float*)d_in[4];
    const float* b1 = (const float*)d_in[5];
    const float* W2 = (const float*)d_in[6];
    const float* b2 = (const float*)d_in[7];
    const float* W3 = (const float*)d_in[8];
    const float* b3 = (const float*)d_in[9];
    const float* Wfc = (const float*)d_in[10];
    const float* bfc = (const float*)d_in[11];
    float* out = (float*)d_out;

    const int M = NNODES, E = NEDGES, G = NGRAPHS;
    const int F1 = 78, F2 = 156, F3 = 312, FC = 489;
    const int* src = eidx;
    const int* dst = eidx + E;

    char* ws = (char*)d_ws;
    size_t off = 0;
    auto alloc = [&](size_t bytes) {
        void* p = ws + off;
        off += (bytes + 255) & ~(size_t)255;
        return p;
    };
    float* buf1 = (float*)alloc((size_t)M * F3 * 4);
    float* buf2 = (float*)alloc((size_t)M * F3 * 4);
    float* dis  = (float*)alloc((size_t)M * 4);
    float* nrm  = (float*)alloc((size_t)E * 4);
    int*   cnt  = (int*)alloc((size_t)M * 4);
    float* g    = (float*)alloc((size_t)G * F3 * 4);
    float* fcb  = (float*)alloc((size_t)G * FC * 4);

    // degree / dis / norm (constant across layers)
    hipMemsetAsync(cnt, 0, (size_t)M * 4, stream);
    deg_count<<<(E + 255) / 256, 256, 0, stream>>>(dst, cnt, E);
    compute_dis<<<(M + 255) / 256, 256, 0, stream>>>(cnt, dis, M);
    edge_norm<<<(E + 255) / 256, 256, 0, stream>>>(src, dst, dis, nrm, E);

    // ---- layer 1: x(78) -> h1(78) in buf1
    gemm_tiled<<<dim3((M + BM - 1) / BM, (F1 + BN - 1) / BN), 256, 0, stream>>>(x, W1, buf2, M, F1, F1);
    hipMemsetAsync(buf1, 0, (size_t)M * F1 * 4, stream);
    scatter_edges<<<(E + 3) / 4, 256, 0, stream>>>(buf2, src, dst, nrm, buf1, E, F1);
    post_layer<<<(M * F1 + 255) / 256, 256, 0, stream>>>(buf1, buf2, dis, b1, M, F1);

    // ---- layer 2: h1(78) -> h2(156) in buf1
    gemm_tiled<<<dim3((M + BM - 1) / BM, (F2 + BN - 1) / BN), 256, 0, stream>>>(buf1, W2, buf2, M, F1, F2);
    hipMemsetAsync(buf1, 0, (size_t)M * F2 * 4, stream);
    scatter_edges<<<(E + 3) / 4, 256, 0, stream>>>(buf2, src, dst, nrm, buf1, E, F2);
    post_layer<<<(M * F2 + 255) / 256, 256, 0, stream>>>(buf1, buf2, dis, b2, M, F2);

    // ---- layer 3: h2(156) -> h3(312) in buf1
    gemm_tiled<<<dim3((M + BM - 1) / BM, (F3 + BN - 1) / BN), 256, 0, stream>>>(buf1, W3, buf2, M, F2, F3);
    hipMemsetAsync(buf1, 0, (size_t)M * F3 * 4, stream);
    scatter_edges<<<(E + 3) / 4, 256, 0, stream>>>(buf2, src, dst, nrm, buf1, E, F3);
    post_layer<<<(M * F3 + 255) / 256, 256, 0, stream>>>(buf1, buf2, dis, b3, M, F3);

    // ---- global max pool
    hipMemsetAsync(g, 0, (size_t)G * F3 * 4, stream);
    pool_max<<<(M * F3 + 255) / 256, 256, 0, stream>>>(buf1, batch, g, M, F3);

    // ---- FC + epilogue
    gemm_tiled<<<dim3((G + BM - 1) / BM, (FC + BN - 1) / BN), 256, 0, stream>>>(g, Wfc, fcb, G, F3, FC);
    final_ep<<<(G * FC + 255) / 256, 256, 0, stream>>>(fcb, bfc, drug2, out, G * FC, FC);
}

// Round 2
// 775.583 us; speedup vs baseline: 2.7531x; 2.7531x over previous
//
#include <hip/hip_runtime.h>

#define NNODES 50000
#define NEDGES 800000
#define NGRAPHS 2048

// ---------------- degree ----------------
__global__ void deg_count(const int* __restrict__ dst, int* __restrict__ cnt, int E) {
    int e = blockIdx.x * blockDim.x + threadIdx.x;
    if (e < E) atomicAdd(&cnt[dst[e]], 1);
}

__global__ void compute_dis(const int* __restrict__ cnt, float* __restrict__ dis, int M) {
    int n = blockIdx.x * blockDim.x + threadIdx.x;
    if (n < M) dis[n] = rsqrtf((float)(cnt[n] + 1));  // +1 self-loop
}

// ---------------- CSR build: block-level exclusive scan ----------------
__global__ void block_scan(const int* __restrict__ cnt, int* __restrict__ lp,
                           int* __restrict__ bsum, int M) {
    __shared__ int s[256];
    int t = threadIdx.x;
    int n = blockIdx.x * 256 + t;
    int v = (n < M) ? cnt[n] : 0;
    s[t] = v;
    __syncthreads();
    #pragma unroll
    for (int off = 1; off < 256; off <<= 1) {
        int u = (t >= off) ? s[t - off] : 0;
        __syncthreads();
        s[t] += u;
        __syncthreads();
    }
    if (n < M) lp[n] = s[t] - v;            // exclusive within block
    if (t == 255) bsum[blockIdx.x] = s[255]; // block total
}

__global__ void scan_bsum(int* __restrict__ bsum, int NB) {
    __shared__ int s[256];
    int t = threadIdx.x;
    int v = (t < NB) ? bsum[t] : 0;
    s[t] = v;
    __syncthreads();
    #pragma unroll
    for (int off = 1; off < 256; off <<= 1) {
        int u = (t >= off) ? s[t - off] : 0;
        __syncthreads();
        s[t] += u;
        __syncthreads();
    }
    if (t < NB) bsum[t] = s[t] - v;         // exclusive across blocks
}

__global__ void finalize_rowptr(int* __restrict__ rowptr, int* __restrict__ cursor,
                                const int* __restrict__ bsum, int M, int E) {
    int n = blockIdx.x * blockDim.x + threadIdx.x;
    if (n < M) {
        int v = rowptr[n] + bsum[n >> 8];
        rowptr[n] = v;
        cursor[n] = v;
    }
    if (n == 0) rowptr[M] = E;
}

__global__ void fill_csr(const int* __restrict__ src, const int* __restrict__ dst,
                         const float* __restrict__ dis, int* __restrict__ cursor,
                         int* __restrict__ csr_src, float* __restrict__ csr_nrm, int E) {
    int e = blockIdx.x * blockDim.x + threadIdx.x;
    if (e >= E) return;
    int s = src[e], d = dst[e];
    int pos = atomicAdd(&cursor[d], 1);
    csr_src[pos] = s;
    csr_nrm[pos] = dis[s] * dis[d];
}

// ---------------- gather aggregation: agg[d] = sum_in h[src]*nrm + h[d]*dis^2 ----------------
// one wave (64 lanes) per dst node; accumulate in registers
template <int F>
__global__ __launch_bounds__(256) void gather_agg(const float* __restrict__ h,
                                                  const int* __restrict__ rowptr,
                                                  const int* __restrict__ csr_src,
                                                  const float* __restrict__ csr_nrm,
                                                  const float* __restrict__ dis,
                                                  float* __restrict__ agg) {
    constexpr int NR = (F + 63) / 64;
    int node = blockIdx.x * 4 + (threadIdx.x >> 6);
    if (node >= NNODES) return;
    int lane = threadIdx.x & 63;
    float acc[NR] = {};
    int beg = rowptr[node], end = rowptr[node + 1];
    for (int i = beg; i < end; ++i) {
        int s = csr_src[i];
        float nm = csr_nrm[i];
        const float* hr = h + (size_t)s * F;
        #pragma unroll
        for (int r = 0; r < NR; ++r) {
            int f = lane + r * 64;
            if (f < F) acc[r] += hr[f] * nm;
        }
    }
    float di = dis[node];
    float d2 = di * di;
    const float* hs = h + (size_t)node * F;
    float* ar = agg + (size_t)node * F;
    #pragma unroll
    for (int r = 0; r < NR; ++r) {
        int f = lane + r * 64;
        if (f < F) ar[f] = acc[r] + hs[f] * d2;
    }
}

// ---------------- tiled f32 GEMM with fused epilogue ----------------
// C[M,N] = op(A[M,K] @ W[K,N] + bias) [+ addend], op = relu if relu!=0
#define BM 64
#define BN 64
#define BK 16
__global__ __launch_bounds__(256) void gemm_tiled(const float* __restrict__ A,
                                                  const float* __restrict__ W,
                                                  float* __restrict__ C,
                                                  const float* __restrict__ bias,
                                                  const float* __restrict__ addend,
                                                  int relu, int M, int K, int N) {
    __shared__ float As[BK][BM + 1];
    __shared__ float Bs[BK][BN + 1];
    int bm = blockIdx.x * BM;
    int bn = blockIdx.y * BN;
    int tid = threadIdx.x;
    int tr = (tid / 16) * 4;
    int tc = (tid % 16) * 4;
    float acc[4][4] = {};
    for (int k0 = 0; k0 < K; k0 += BK) {
        #pragma unroll
        for (int i = 0; i < 4; ++i) {
            int idx = tid + i * 256;
            int r = idx / BK, k = idx % BK;
            int gr = bm + r, gk = k0 + k;
            float v = 0.f;
            if (gr < M && gk < K) v = A[(size_t)gr * K + gk];
            As[k][r] = v;
        }
        #pragma unroll
        for (int i = 0; i < 4; ++i) {
            int idx = tid + i * 256;
            int k = idx / BN, c = idx % BN;
            int gk = k0 + k, gc = bn + c;
            float v = 0.f;
            if (gk < K && gc < N) v = W[(size_t)gk * N + gc];
            Bs[k][c] = v;
        }
        __syncthreads();
        #pragma unroll
        for (int k = 0; k < BK; ++k) {
            float a[4], b[4];
            #pragma unroll
            for (int i = 0; i < 4; ++i) a[i] = As[k][tr + i];
            #pragma unroll
            for (int j = 0; j < 4; ++j) b[j] = Bs[k][tc + j];
            #pragma unroll
            for (int i = 0; i < 4; ++i)
                #pragma unroll
                for (int j = 0; j < 4; ++j) acc[i][j] += a[i] * b[j];
        }
        __syncthreads();
    }
    #pragma unroll
    for (int i = 0; i < 4; ++i) {
        int gr = bm + tr + i;
        if (gr >= M) continue;
        #pragma unroll
        for (int j = 0; j < 4; ++j) {
            int gc = bn + tc + j;
            if (gc >= N) continue;
            float v = acc[i][j];
            if (bias) v += bias[gc];
            if (relu) v = fmaxf(v, 0.f);
            if (addend) v += addend[(size_t)gr * N + gc];
            C[(size_t)gr * N + gc] = v;
        }
    }
}

// ---------------- global max pool (h >= 0 post-relu -> int atomicMax valid) ----------------
__global__ void pool_max(const float* __restrict__ h, const int* __restrict__ batch,
                         float* __restrict__ g, int M, int N) {
    int idx = blockIdx.x * blockDim.x + threadIdx.x;
    if (idx >= M * N) return;
    int n = idx / N, f = idx % N;
    float v = h[idx];
    atomicMax((int*)&g[(size_t)batch[n] * N + f], __float_as_int(v));
}

extern "C" void kernel_launch(void* const* d_in, const int* in_sizes, int n_in,
                              void* d_out, int out_size, void* d_ws, size_t ws_size,
                              hipStream_t stream) {
    const float* x     = (const float*)d_in[0];
    const int*   eidx  = (const int*)d_in[1];
    const int*   batch = (const int*)d_in[2];
    const float* drug2 = (const float*)d_in[3];
    const float* W1 = (const float*)d_in[4];
    const float* b1 = (const float*)d_in[5];
    const float* W2 = (const float*)d_in[6];
    const float* b2 = (const float*)d_in[7];
    const float* W3 = (const float*)d_in[8];
    const float* b3 = (const float*)d_in[9];
    const float* Wfc = (const float*)d_in[10];
    const float* bfc = (const float*)d_in[11];
    float* out = (float*)d_out;

    const int M = NNODES, E = NEDGES, G = NGRAPHS;
    const int F1 = 78, F2 = 156, F3 = 312, FC = 489;
    const int* src = eidx;
    const int* dst = eidx + E;
    const int NB = (M + 255) / 256;  // 196 scan blocks

    char* ws = (char*)d_ws;
    size_t off = 0;
    auto alloc = [&](size_t bytes) {
        void* p = ws + off;
        off += (bytes + 255) & ~(size_t)255;
        return p;
    };
    float* aggb   = (float*)alloc((size_t)M * F2 * 4);   // agg scratch (max 156)
    float* hA     = (float*)alloc((size_t)M * F3 * 4);   // h1 then h3
    float* hB     = (float*)alloc((size_t)M * F2 * 4);   // h2
    float* dis    = (float*)alloc((size_t)M * 4);
    int*   cnt    = (int*)alloc((size_t)M * 4);
    int*   rowptr = (int*)alloc((size_t)(M + 1) * 4);
    int*   cursor = (int*)alloc((size_t)M * 4);
    int*   bsum   = (int*)alloc(1024);
    int*   csr_src = (int*)alloc((size_t)E * 4);
    float* csr_nrm = (float*)alloc((size_t)E * 4);
    float* g      = (float*)alloc((size_t)G * F3 * 4);

    // ---- CSR build (once; reused by all 3 layers)
    hipMemsetAsync(cnt, 0, (size_t)M * 4, stream);
    deg_count<<<(E + 255) / 256, 256, 0, stream>>>(dst, cnt, E);
    compute_dis<<<NB, 256, 0, stream>>>(cnt, dis, M);
    block_scan<<<NB, 256, 0, stream>>>(cnt, rowptr, bsum, M);
    scan_bsum<<<1, 256, 0, stream>>>(bsum, NB);
    finalize_rowptr<<<NB, 256, 0, stream>>>(rowptr, cursor, bsum, M, E);
    fill_csr<<<(E + 255) / 256, 256, 0, stream>>>(src, dst, dis, cursor, csr_src, csr_nrm, E);

    const int GATHER_GRID = (M + 3) / 4;

    // ---- layer 1: agg = Ahat@x (78); h1 = relu(agg@W1 + b1) -> hA
    gather_agg<78><<<GATHER_GRID, 256, 0, stream>>>(x, rowptr, csr_src, csr_nrm, dis, aggb);
    gemm_tiled<<<dim3((M + BM - 1) / BM, (F1 + BN - 1) / BN), 256, 0, stream>>>(
        aggb, W1, hA, b1, nullptr, 1, M, F1, F1);

    // ---- layer 2: agg = Ahat@h1 (78); h2 = relu(agg@W2 + b2) -> hB
    gather_agg<78><<<GATHER_GRID, 256, 0, stream>>>(hA, rowptr, csr_src, csr_nrm, dis, aggb);
    gemm_tiled<<<dim3((M + BM - 1) / BM, (F2 + BN - 1) / BN), 256, 0, stream>>>(
        aggb, W2, hB, b2, nullptr, 1, M, F1, F2);

    // ---- layer 3: agg = Ahat@h2 (156); h3 = relu(agg@W3 + b3) -> hA
    gather_agg<156><<<GATHER_GRID, 256, 0, stream>>>(hB, rowptr, csr_src, csr_nrm, dis, aggb);
    gemm_tiled<<<dim3((M + BM - 1) / BM, (F3 + BN - 1) / BN), 256, 0, stream>>>(
        aggb, W3, hA, b3, nullptr, 1, M, F2, F3);

    // ---- global max pool (init 0 == isfinite-guard semantics, h3 >= 0)
    hipMemsetAsync(g, 0, (size_t)G * F3 * 4, stream);
    pool_max<<<(M * F3 + 255) / 256, 256, 0, stream>>>(hA, batch, g, M, F3);

    // ---- FC: out = relu(g@Wfc + bfc) + drug2 (fully fused epilogue)
    gemm_tiled<<<dim3((G + BM - 1) / BM, (FC + BN - 1) / BN), 256, 0, stream>>>(
        g, Wfc, out, bfc, drug2, 1, G, F3, FC);
}

// Round 3
// 446.945 us; speedup vs baseline: 4.7775x; 1.7353x over previous
//
#include <hip/hip_runtime.h>

#define NNODES 50000
#define NEDGES 800000
#define NGRAPHS 2048

typedef __attribute__((ext_vector_type(8))) short bf16x8;
typedef __attribute__((ext_vector_type(4))) float f32x4;

__device__ __forceinline__ float bf2f(ushort u) {
    return __uint_as_float(((uint)u) << 16);
}
__device__ __forceinline__ ushort f2bf(float f) {
    uint u = __float_as_uint(f);
    return (ushort)((u + 0x7fff + ((u >> 16) & 1)) >> 16);  // RNE
}

// ---------------- degree ----------------
__global__ void deg_count(const int* __restrict__ dst, int* __restrict__ cnt, int E) {
    int e = blockIdx.x * blockDim.x + threadIdx.x;
    if (e < E) atomicAdd(&cnt[dst[e]], 1);
}

__global__ void compute_dis(const int* __restrict__ cnt, float* __restrict__ dis, int M) {
    int n = blockIdx.x * blockDim.x + threadIdx.x;
    if (n < M) dis[n] = rsqrtf((float)(cnt[n] + 1));  // +1 self-loop
}

// ---------------- CSR build ----------------
__global__ void block_scan(const int* __restrict__ cnt, int* __restrict__ lp,
                           int* __restrict__ bsum, int M) {
    __shared__ int s[256];
    int t = threadIdx.x;
    int n = blockIdx.x * 256 + t;
    int v = (n < M) ? cnt[n] : 0;
    s[t] = v;
    __syncthreads();
    #pragma unroll
    for (int off = 1; off < 256; off <<= 1) {
        int u = (t >= off) ? s[t - off] : 0;
        __syncthreads();
        s[t] += u;
        __syncthreads();
    }
    if (n < M) lp[n] = s[t] - v;
    if (t == 255) bsum[blockIdx.x] = s[255];
}

__global__ void scan_bsum(int* __restrict__ bsum, int NB) {
    __shared__ int s[256];
    int t = threadIdx.x;
    int v = (t < NB) ? bsum[t] : 0;
    s[t] = v;
    __syncthreads();
    #pragma unroll
    for (int off = 1; off < 256; off <<= 1) {
        int u = (t >= off) ? s[t - off] : 0;
        __syncthreads();
        s[t] += u;
        __syncthreads();
    }
    if (t < NB) bsum[t] = s[t] - v;
}

__global__ void finalize_rowptr(int* __restrict__ rowptr, int* __restrict__ cursor,
                                const int* __restrict__ bsum, int M, int E) {
    int n = blockIdx.x * blockDim.x + threadIdx.x;
    if (n < M) {
        int v = rowptr[n] + bsum[n >> 8];
        rowptr[n] = v;
        cursor[n] = v;
    }
    if (n == 0) rowptr[M] = E;
}

__global__ void fill_csr(const int* __restrict__ src, const int* __restrict__ dst,
                         const float* __restrict__ dis, int* __restrict__ cursor,
                         int* __restrict__ csr_src, float* __restrict__ csr_nrm, int E) {
    int e = blockIdx.x * blockDim.x + threadIdx.x;
    if (e >= E) return;
    int s = src[e], d = dst[e];
    int pos = atomicAdd(&cursor[d], 1);
    csr_src[pos] = s;
    csr_nrm[pos] = dis[s] * dis[d];
}

// ---------------- input cast / weight prep ----------------
__global__ void cast_x(const float* __restrict__ x, ushort* __restrict__ xb,
                       int M, int K, int Kp) {
    int idx = blockIdx.x * blockDim.x + threadIdx.x;
    if (idx >= M * Kp) return;
    int n = idx / Kp, k = idx % Kp;
    xb[idx] = (k < K) ? f2bf(x[(size_t)n * K + k]) : (ushort)0;
}

// Wt[n][k] = W[k][n], bf16, zero-padded to [Np][Kp]
__global__ void prep_w(const float* __restrict__ W, ushort* __restrict__ Wt,
                       int K, int N, int Kp, int Np) {
    int idx = blockIdx.x * blockDim.x + threadIdx.x;
    if (idx >= Kp * Np) return;
    int n = idx / Kp, k = idx % Kp;
    Wt[idx] = (k < K && n < N) ? f2bf(W[(size_t)k * N + n]) : (ushort)0;
}

// ---------------- gather aggregation (bf16 in/out, f32 accum) ----------------
// PIN/POUT in u32 pairs (2 bf16 each). one wave per dst node.
template <int PIN, int POUT>
__global__ __launch_bounds__(256) void gather_bf16(const uint* __restrict__ h,
                                                   const int* __restrict__ rowptr,
                                                   const int* __restrict__ csr_src,
                                                   const float* __restrict__ csr_nrm,
                                                   const float* __restrict__ dis,
                                                   uint* __restrict__ agg) {
    constexpr int NR = (POUT + 63) / 64;
    int node = blockIdx.x * 4 + (threadIdx.x >> 6);
    if (node >= NNODES) return;
    int lane = threadIdx.x & 63;
    float accL[NR] = {}, accH[NR] = {};
    int beg = rowptr[node], end = rowptr[node + 1];
    for (int i = beg; i < end; ++i) {
        int s = csr_src[i];
        float nm = csr_nrm[i];
        const uint* hr = h + (size_t)s * PIN;
        #pragma unroll
        for (int r = 0; r < NR; ++r) {
            int p = lane + r * 64;
            if (p < PIN) {
                uint v = hr[p];
                accL[r] += bf2f((ushort)(v & 0xffff)) * nm;
                accH[r] += bf2f((ushort)(v >> 16)) * nm;
            }
        }
    }
    float di = dis[node];
    float d2 = di * di;
    const uint* hs = h + (size_t)node * PIN;
    uint* ar = agg + (size_t)node * POUT;
    #pragma unroll
    for (int r = 0; r < NR; ++r) {
        int p = lane + r * 64;
        if (p < POUT) {
            float l = accL[r], hh = accH[r];
            if (p < PIN) {
                uint v = hs[p];
                l += bf2f((ushort)(v & 0xffff)) * d2;
                hh += bf2f((ushort)(v >> 16)) * d2;
            }
            ar[p] = (uint)f2bf(l) | ((uint)f2bf(hh) << 16);
        }
    }
}

// ---------------- MFMA bf16 GEMM: C = epi(A[M][Kp] @ Wt[Np][Kp]^T) ----------------
// block 64x64, 4 waves (2x2), each wave 32x32 via 2x2 16x16x32 frags.
// EPI=0: bf16 out [M][Np], relu(acc+bias) for col<Nreal else 0.
// EPI=1: f32 out [M][Nreal], relu(acc+bias)+addend.
template <int EPI>
__global__ __launch_bounds__(256) void gemm_mfma(const ushort* __restrict__ A,
                                                 const ushort* __restrict__ Bt,
                                                 ushort* __restrict__ Cb,
                                                 float* __restrict__ Cf,
                                                 const float* __restrict__ bias,
                                                 const float* __restrict__ addend,
                                                 int M, int Kp, int Np, int Nreal) {
    __shared__ ushort Asl[64 * 32];
    __shared__ ushort Bsl[64 * 32];
    const int tid = threadIdx.x;
    const int lane = tid & 63;
    const int wid = tid >> 6;
    const int wm = (wid >> 1) * 32, wn = (wid & 1) * 32;
    const int bm = blockIdx.x * 64, bn = blockIdx.y * 64;

    const int sr = tid >> 2;                  // staging row 0..63
    const int sc = tid & 3;                   // logical 8-elem chunk
    const int swz = sc ^ ((sr >> 1) & 3);     // bank swizzle
    const int lc = lane >> 4;                 // frag k-chunk

    f32x4 acc[2][2] = {};
    for (int k0 = 0; k0 < Kp; k0 += 32) {
        bf16x8 av = {};
        int gr = bm + sr;
        if (gr < M) av = *(const bf16x8*)&A[(size_t)gr * Kp + k0 + sc * 8];
        *(bf16x8*)&Asl[sr * 32 + swz * 8] = av;
        bf16x8 bv = {};
        int gn = bn + sr;
        if (gn < Np) bv = *(const bf16x8*)&Bt[(size_t)gn * Kp + k0 + sc * 8];
        *(bf16x8*)&Bsl[sr * 32 + swz * 8] = bv;
        __syncthreads();
        bf16x8 af[2], bfr[2];
        #pragma unroll
        for (int m = 0; m < 2; ++m) {
            int r = wm + m * 16 + (lane & 15);
            int pc = lc ^ ((r >> 1) & 3);
            af[m] = *(const bf16x8*)&Asl[r * 32 + pc * 8];
        }
        #pragma unroll
        for (int n = 0; n < 2; ++n) {
            int r = wn + n * 16 + (lane & 15);
            int pc = lc ^ ((r >> 1) & 3);
            bfr[n] = *(const bf16x8*)&Bsl[r * 32 + pc * 8];
        }
        #pragma unroll
        for (int m = 0; m < 2; ++m)
            #pragma unroll
            for (int n = 0; n < 2; ++n)
                acc[m][n] = __builtin_amdgcn_mfma_f32_16x16x32_bf16(af[m], bfr[n], acc[m][n], 0, 0, 0);
        __syncthreads();
    }
    #pragma unroll
    for (int m = 0; m < 2; ++m) {
        #pragma unroll
        for (int n = 0; n < 2; ++n) {
            int gc = bn + wn + n * 16 + (lane & 15);
            #pragma unroll
            for (int j = 0; j < 4; ++j) {
                int gr = bm + wm + m * 16 + (lane >> 4) * 4 + j;
                if (gr >= M) continue;
                float v = acc[m][n][j];
                if (EPI == 0) {
                    if (gc < Np) {
                        float o = (gc < Nreal) ? fmaxf(v + bias[gc], 0.f) : 0.f;
                        Cb[(size_t)gr * Np + gc] = f2bf(o);
                    }
                } else {
                    if (gc < Nreal) {
                        float o = fmaxf(v + bias[gc], 0.f) + addend[(size_t)gr * Nreal + gc];
                        Cf[(size_t)gr * Nreal + gc] = o;
                    }
                }
            }
        }
    }
}

// ---------------- per-graph segment bounds (batch is sorted) ----------------
__global__ void graph_bounds(const int* __restrict__ batch, int* __restrict__ gstart,
                             int M, int G) {
    int n = blockIdx.x * blockDim.x + threadIdx.x;
    if (n >= M) return;
    int b = batch[n];
    int bp = (n == 0) ? -1 : batch[n - 1];
    for (int gg = bp + 1; gg <= b; ++gg) gstart[gg] = n;
    if (n == M - 1) {
        for (int gg = b + 1; gg <= G; ++gg) gstart[gg] = M;
    }
}

// ---------------- segmented max pool: block per graph, bf16 out ----------------
__global__ void pool_max_seg(const uint* __restrict__ h3, const int* __restrict__ gstart,
                             uint* __restrict__ gb, int PAIRS) {
    int g = blockIdx.x;
    int s = gstart[g], e = gstart[g + 1];
    for (int p = threadIdx.x; p < PAIRS; p += blockDim.x) {
        float mL = 0.f, mH = 0.f;  // h3 >= 0; empty graph -> 0 (isfinite guard)
        for (int n = s; n < e; ++n) {
            uint v = h3[(size_t)n * PAIRS + p];
            mL = fmaxf(mL, bf2f((ushort)(v & 0xffff)));
            mH = fmaxf(mH, bf2f((ushort)(v >> 16)));
        }
        gb[(size_t)g * PAIRS + p] = (uint)f2bf(mL) | ((uint)f2bf(mH) << 16);
    }
}

extern "C" void kernel_launch(void* const* d_in, const int* in_sizes, int n_in,
                              void* d_out, int out_size, void* d_ws, size_t ws_size,
                              hipStream_t stream) {
    const float* x     = (const float*)d_in[0];
    const int*   eidx  = (const int*)d_in[1];
    const int*   batch = (const int*)d_in[2];
    const float* drug2 = (const float*)d_in[3];
    const float* W1 = (const float*)d_in[4];
    const float* b1 = (const float*)d_in[5];
    const float* W2 = (const float*)d_in[6];
    const float* b2 = (const float*)d_in[7];
    const float* W3 = (const float*)d_in[8];
    const float* b3 = (const float*)d_in[9];
    const float* Wfc = (const float*)d_in[10];
    const float* bfc = (const float*)d_in[11];
    float* out = (float*)d_out;

    const int M = NNODES, E = NEDGES, G = NGRAPHS;
    // real dims
    const int F1 = 78, F2 = 156, F3 = 312, FC = 489;
    // padded dims
    const int Kp1 = 96, Np1 = 80;     // layer1: K=78->96, N=78->80
    const int Kp2 = 96, Np2 = 160;    // layer2: K=78->96, N=156->160
    const int Kp3 = 160, Np3 = 320;   // layer3: K=156->160, N=312->320
    const int Kpf = 320, Npf = 496;   // fc:     K=312->320, N=489->496

    const int* src = eidx;
    const int* dst = eidx + E;
    const int NB = (M + 255) / 256;

    char* ws = (char*)d_ws;
    size_t off = 0;
    auto alloc = [&](size_t bytes) {
        void* p = ws + off;
        off += (bytes + 255) & ~(size_t)255;
        return p;
    };
    ushort* xb   = (ushort*)alloc((size_t)M * Kp1 * 2);
    ushort* h1   = (ushort*)alloc((size_t)M * Np1 * 2);
    ushort* h2   = (ushort*)alloc((size_t)M * Np2 * 2);
    ushort* h3   = (ushort*)alloc((size_t)M * Np3 * 2);
    ushort* agg  = (ushort*)alloc((size_t)M * Kp3 * 2);   // max Kp = 160
    ushort* W1t  = (ushort*)alloc((size_t)Np1 * Kp1 * 2);
    ushort* W2t  = (ushort*)alloc((size_t)Np2 * Kp2 * 2);
    ushort* W3t  = (ushort*)alloc((size_t)Np3 * Kp3 * 2);
    ushort* Wfct = (ushort*)alloc((size_t)Npf * Kpf * 2);
    ushort* gb   = (ushort*)alloc((size_t)G * Kpf * 2);
    float* dis    = (float*)alloc((size_t)M * 4);
    int*   cnt    = (int*)alloc((size_t)M * 4);
    int*   rowptr = (int*)alloc((size_t)(M + 1) * 4);
    int*   cursor = (int*)alloc((size_t)M * 4);
    int*   bsum   = (int*)alloc(1024);
    int*   csr_src = (int*)alloc((size_t)E * 4);
    float* csr_nrm = (float*)alloc((size_t)E * 4);
    int*   gstart  = (int*)alloc((size_t)(G + 1) * 4);

    // ---- CSR build + per-graph bounds
    hipMemsetAsync(cnt, 0, (size_t)M * 4, stream);
    deg_count<<<(E + 255) / 256, 256, 0, stream>>>(dst, cnt, E);
    compute_dis<<<NB, 256, 0, stream>>>(cnt, dis, M);
    block_scan<<<NB, 256, 0, stream>>>(cnt, rowptr, bsum, M);
    scan_bsum<<<1, 256, 0, stream>>>(bsum, NB);
    finalize_rowptr<<<NB, 256, 0, stream>>>(rowptr, cursor, bsum, M, E);
    fill_csr<<<(E + 255) / 256, 256, 0, stream>>>(src, dst, dis, cursor, csr_src, csr_nrm, E);
    graph_bounds<<<NB, 256, 0, stream>>>(batch, gstart, M, G);

    // ---- casts / weight prep
    cast_x<<<(M * Kp1 + 255) / 256, 256, 0, stream>>>(x, xb, M, F1, Kp1);
    prep_w<<<(Np1 * Kp1 + 255) / 256, 256, 0, stream>>>(W1, W1t, F1, F1, Kp1, Np1);
    prep_w<<<(Np2 * Kp2 + 255) / 256, 256, 0, stream>>>(W2, W2t, F1, F2, Kp2, Np2);
    prep_w<<<(Np3 * Kp3 + 255) / 256, 256, 0, stream>>>(W3, W3t, F2, F3, Kp3, Np3);
    prep_w<<<(Npf * Kpf + 255) / 256, 256, 0, stream>>>(Wfc, Wfct, F3, FC, Kpf, Npf);

    const int GG = (M + 3) / 4;
    const int GMX = (M + 63) / 64;

    // ---- layer 1: agg = Ahat@xb (96 wide); h1 = relu(agg@W1+b1) bf16 [M][80]
    gather_bf16<48, 48><<<GG, 256, 0, stream>>>((const uint*)xb, rowptr, csr_src, csr_nrm, dis, (uint*)agg);
    gemm_mfma<0><<<dim3(GMX, Np1 / 64 + 1), 256, 0, stream>>>(agg, W1t, h1, nullptr, b1, nullptr, M, Kp1, Np1, F1);

    // ---- layer 2: agg = Ahat@h1; h2 = relu(agg@W2+b2) bf16 [M][160]
    gather_bf16<40, 48><<<GG, 256, 0, stream>>>((const uint*)h1, rowptr, csr_src, csr_nrm, dis, (uint*)agg);
    gemm_mfma<0><<<dim3(GMX, Np2 / 64 + 1), 256, 0, stream>>>(agg, W2t, h2, nullptr, b2, nullptr, M, Kp2, Np2, F2);

    // ---- layer 3: agg = Ahat@h2; h3 = relu(agg@W3+b3) bf16 [M][320]
    gather_bf16<80, 80><<<GG, 256, 0, stream>>>((const uint*)h2, rowptr, csr_src, csr_nrm, dis, (uint*)agg);
    gemm_mfma<0><<<dim3(GMX, Np3 / 64), 256, 0, stream>>>(agg, W3t, h3, nullptr, b3, nullptr, M, Kp3, Np3, F3);

    // ---- segmented max pool -> gb bf16 [G][320]
    pool_max_seg<<<G, 256, 0, stream>>>((const uint*)h3, gstart, (uint*)gb, Kpf / 2);

    // ---- FC: out = relu(gb@Wfc+bfc)+drug2, f32 [2048][489]
    gemm_mfma<1><<<dim3((G + 63) / 64, (Npf + 63) / 64), 256, 0, stream>>>(gb, Wfct, nullptr, out, bfc, drug2, G, Kpf, Npf, FC);
}

// Round 4
// 301.428 us; speedup vs baseline: 7.0839x; 1.4828x over previous
//
#include <hip/hip_runtime.h>

#define NNODES 50000
#define NEDGES 800000
#define NGRAPHS 2048

typedef __attribute__((ext_vector_type(8))) short bf16x8;
typedef __attribute__((ext_vector_type(4))) float f32x4;

__device__ __forceinline__ float bf2f(ushort u) {
    return __uint_as_float(((uint)u) << 16);
}
__device__ __forceinline__ ushort f2bf(float f) {
    uint u = __float_as_uint(f);
    return (ushort)((u + 0x7fff + ((u >> 16) & 1)) >> 16);  // RNE
}

// ---------------- degree ----------------
__global__ void deg_count(const int* __restrict__ dst, int* __restrict__ cnt, int E) {
    int e = blockIdx.x * blockDim.x + threadIdx.x;
    if (e < E) atomicAdd(&cnt[dst[e]], 1);
}

__global__ void compute_dis(const int* __restrict__ cnt, float* __restrict__ dis, int M) {
    int n = blockIdx.x * blockDim.x + threadIdx.x;
    if (n < M) dis[n] = rsqrtf((float)(cnt[n] + 1));  // +1 self-loop
}

// ---------------- CSR build ----------------
__global__ void block_scan(const int* __restrict__ cnt, int* __restrict__ lp,
                           int* __restrict__ bsum, int M) {
    __shared__ int s[256];
    int t = threadIdx.x;
    int n = blockIdx.x * 256 + t;
    int v = (n < M) ? cnt[n] : 0;
    s[t] = v;
    __syncthreads();
    #pragma unroll
    for (int off = 1; off < 256; off <<= 1) {
        int u = (t >= off) ? s[t - off] : 0;
        __syncthreads();
        s[t] += u;
        __syncthreads();
    }
    if (n < M) lp[n] = s[t] - v;
    if (t == 255) bsum[blockIdx.x] = s[255];
}

__global__ void scan_bsum(int* __restrict__ bsum, int NB) {
    __shared__ int s[256];
    int t = threadIdx.x;
    int v = (t < NB) ? bsum[t] : 0;
    s[t] = v;
    __syncthreads();
    #pragma unroll
    for (int off = 1; off < 256; off <<= 1) {
        int u = (t >= off) ? s[t - off] : 0;
        __syncthreads();
        s[t] += u;
        __syncthreads();
    }
    if (t < NB) bsum[t] = s[t] - v;
}

__global__ void finalize_rowptr(int* __restrict__ rowptr, int* __restrict__ cursor,
                                const int* __restrict__ bsum, int M, int E) {
    int n = blockIdx.x * blockDim.x + threadIdx.x;
    if (n < M) {
        int v = rowptr[n] + bsum[n >> 8];
        rowptr[n] = v;
        cursor[n] = v;
    }
    if (n == 0) rowptr[M] = E;
}

__global__ void fill_csr(const int* __restrict__ src, const int* __restrict__ dst,
                         const float* __restrict__ dis, int* __restrict__ cursor,
                         int* __restrict__ csr_src, float* __restrict__ csr_nrm, int E) {
    int e = blockIdx.x * blockDim.x + threadIdx.x;
    if (e >= E) return;
    int s = src[e], d = dst[e];
    int pos = atomicAdd(&cursor[d], 1);
    csr_src[pos] = s;
    csr_nrm[pos] = dis[s] * dis[d];
}

// ---------------- input cast / weight prep ----------------
__global__ void cast_x(const float* __restrict__ x, ushort* __restrict__ xb,
                       int M, int K, int Kp) {
    int idx = blockIdx.x * blockDim.x + threadIdx.x;
    if (idx >= M * Kp) return;
    int n = idx / Kp, k = idx % Kp;
    xb[idx] = (k < K) ? f2bf(x[(size_t)n * K + k]) : (ushort)0;
}

// Wt[n][k] = W[k][n], bf16, zero-padded to [Np][Kp]
__global__ void prep_w(const float* __restrict__ W, ushort* __restrict__ Wt,
                       int K, int N, int Kp, int Np) {
    int idx = blockIdx.x * blockDim.x + threadIdx.x;
    if (idx >= Kp * Np) return;
    int n = idx / Kp, k = idx % Kp;
    Wt[idx] = (k < K && n < N) ? f2bf(W[(size_t)k * N + n]) : (ushort)0;
}

// ---------------- ILP gather: lanes = (sub-edge, uint4-chunk) ----------------
// Row = CH uint4 (= CH*8 bf16). SUB edges in flight per wave, x2 unroll.
// CHOUT >= CH output chunks (extra chunks zero-padded).
__device__ __forceinline__ void acc8(float* acc, uint4 v, float nm) {
    acc[0] += bf2f((ushort)(v.x & 0xffff)) * nm;
    acc[1] += bf2f((ushort)(v.x >> 16)) * nm;
    acc[2] += bf2f((ushort)(v.y & 0xffff)) * nm;
    acc[3] += bf2f((ushort)(v.y >> 16)) * nm;
    acc[4] += bf2f((ushort)(v.z & 0xffff)) * nm;
    acc[5] += bf2f((ushort)(v.z >> 16)) * nm;
    acc[6] += bf2f((ushort)(v.w & 0xffff)) * nm;
    acc[7] += bf2f((ushort)(v.w >> 16)) * nm;
}

template <int CH, int SUB, int CHOUT>
__global__ __launch_bounds__(256) void gather_ilp(const uint4* __restrict__ h,
                                                  const int* __restrict__ rowptr,
                                                  const int* __restrict__ csr_src,
                                                  const float* __restrict__ csr_nrm,
                                                  const float* __restrict__ dis,
                                                  uint4* __restrict__ agg) {
    int node = blockIdx.x * 4 + (threadIdx.x >> 6);
    if (node >= NNODES) return;
    int lane = threadIdx.x & 63;
    int sub = lane / CH;
    int ch = lane % CH;
    bool active = sub < SUB;

    float acc[8] = {};
    int beg = rowptr[node], end = rowptr[node + 1];
    for (int i = beg; i < end; i += 2 * SUB) {
        int e0 = i + sub;
        int e1 = i + SUB + sub;
        bool v0 = active && (e0 < end);
        bool v1 = active && (e1 < end);
        int s0 = v0 ? csr_src[e0] : 0;
        int s1 = v1 ? csr_src[e1] : 0;
        float n0 = v0 ? csr_nrm[e0] : 0.f;
        float n1 = v1 ? csr_nrm[e1] : 0.f;
        uint4 a = v0 ? h[(size_t)s0 * CH + ch] : make_uint4(0, 0, 0, 0);
        uint4 b = v1 ? h[(size_t)s1 * CH + ch] : make_uint4(0, 0, 0, 0);
        acc8(acc, a, n0);
        acc8(acc, b, n1);
    }

    // reduce partials across sub groups (read-only sources -> no contamination)
    float tot[8];
    #pragma unroll
    for (int j = 0; j < 8; ++j) tot[j] = acc[j];
    #pragma unroll
    for (int sb = 1; sb < SUB; ++sb) {
        int srcLane = ch + sb * CH;
        #pragma unroll
        for (int j = 0; j < 8; ++j) tot[j] += __shfl(acc[j], srcLane);
    }

    if (lane < CHOUT) {
        uint4 o = make_uint4(0, 0, 0, 0);
        if (lane < CH) {
            float di = dis[node];
            float d2 = di * di;
            uint4 hs = h[(size_t)node * CH + lane];
            tot[0] += bf2f((ushort)(hs.x & 0xffff)) * d2;
            tot[1] += bf2f((ushort)(hs.x >> 16)) * d2;
            tot[2] += bf2f((ushort)(hs.y & 0xffff)) * d2;
            tot[3] += bf2f((ushort)(hs.y >> 16)) * d2;
            tot[4] += bf2f((ushort)(hs.z & 0xffff)) * d2;
            tot[5] += bf2f((ushort)(hs.z >> 16)) * d2;
            tot[6] += bf2f((ushort)(hs.w & 0xffff)) * d2;
            tot[7] += bf2f((ushort)(hs.w >> 16)) * d2;
            o.x = (uint)f2bf(tot[0]) | ((uint)f2bf(tot[1]) << 16);
            o.y = (uint)f2bf(tot[2]) | ((uint)f2bf(tot[3]) << 16);
            o.z = (uint)f2bf(tot[4]) | ((uint)f2bf(tot[5]) << 16);
            o.w = (uint)f2bf(tot[6]) | ((uint)f2bf(tot[7]) << 16);
        }
        agg[(size_t)node * CHOUT + lane] = o;
    }
}

// ---------------- MFMA bf16 GEMM: C = epi(A[M][Kp] @ Wt[Np][Kp]^T) ----------------
template <int EPI>
__global__ __launch_bounds__(256) void gemm_mfma(const ushort* __restrict__ A,
                                                 const ushort* __restrict__ Bt,
                                                 ushort* __restrict__ Cb,
                                                 float* __restrict__ Cf,
                                                 const float* __restrict__ bias,
                                                 const float* __restrict__ addend,
                                                 int M, int Kp, int Np, int Nreal) {
    __shared__ ushort Asl[64 * 32];
    __shared__ ushort Bsl[64 * 32];
    const int tid = threadIdx.x;
    const int lane = tid & 63;
    const int wid = tid >> 6;
    const int wm = (wid >> 1) * 32, wn = (wid & 1) * 32;
    const int bm = blockIdx.x * 64, bn = blockIdx.y * 64;

    const int sr = tid >> 2;
    const int sc = tid & 3;
    const int swz = sc ^ ((sr >> 1) & 3);
    const int lc = lane >> 4;

    f32x4 acc[2][2] = {};
    for (int k0 = 0; k0 < Kp; k0 += 32) {
        bf16x8 av = {};
        int gr = bm + sr;
        if (gr < M) av = *(const bf16x8*)&A[(size_t)gr * Kp + k0 + sc * 8];
        *(bf16x8*)&Asl[sr * 32 + swz * 8] = av;
        bf16x8 bv = {};
        int gn = bn + sr;
        if (gn < Np) bv = *(const bf16x8*)&Bt[(size_t)gn * Kp + k0 + sc * 8];
        *(bf16x8*)&Bsl[sr * 32 + swz * 8] = bv;
        __syncthreads();
        bf16x8 af[2], bfr[2];
        #pragma unroll
        for (int m = 0; m < 2; ++m) {
            int r = wm + m * 16 + (lane & 15);
            int pc = lc ^ ((r >> 1) & 3);
            af[m] = *(const bf16x8*)&Asl[r * 32 + pc * 8];
        }
        #pragma unroll
        for (int n = 0; n < 2; ++n) {
            int r = wn + n * 16 + (lane & 15);
            int pc = lc ^ ((r >> 1) & 3);
            bfr[n] = *(const bf16x8*)&Bsl[r * 32 + pc * 8];
        }
        #pragma unroll
        for (int m = 0; m < 2; ++m)
            #pragma unroll
            for (int n = 0; n < 2; ++n)
                acc[m][n] = __builtin_amdgcn_mfma_f32_16x16x32_bf16(af[m], bfr[n], acc[m][n], 0, 0, 0);
        __syncthreads();
    }
    #pragma unroll
    for (int m = 0; m < 2; ++m) {
        #pragma unroll
        for (int n = 0; n < 2; ++n) {
            int gc = bn + wn + n * 16 + (lane & 15);
            #pragma unroll
            for (int j = 0; j < 4; ++j) {
                int gr = bm + wm + m * 16 + (lane >> 4) * 4 + j;
                if (gr >= M) continue;
                float v = acc[m][n][j];
                if (EPI == 0) {
                    if (gc < Np) {
                        float o = (gc < Nreal) ? fmaxf(v + bias[gc], 0.f) : 0.f;
                        Cb[(size_t)gr * Np + gc] = f2bf(o);
                    }
                } else {
                    if (gc < Nreal) {
                        float o = fmaxf(v + bias[gc], 0.f) + addend[(size_t)gr * Nreal + gc];
                        Cf[(size_t)gr * Nreal + gc] = o;
                    }
                }
            }
        }
    }
}

// ---------------- per-graph segment bounds (batch is sorted) ----------------
__global__ void graph_bounds(const int* __restrict__ batch, int* __restrict__ gstart,
                             int M, int G) {
    int n = blockIdx.x * blockDim.x + threadIdx.x;
    if (n >= M) return;
    int b = batch[n];
    int bp = (n == 0) ? -1 : batch[n - 1];
    for (int gg = bp + 1; gg <= b; ++gg) gstart[gg] = n;
    if (n == M - 1) {
        for (int gg = b + 1; gg <= G; ++gg) gstart[gg] = M;
    }
}

// ---------------- segmented max pool: block per graph, bf16 out ----------------
__global__ void pool_max_seg(const uint* __restrict__ h3, const int* __restrict__ gstart,
                             uint* __restrict__ gb, int PAIRS) {
    int g = blockIdx.x;
    int s = gstart[g], e = gstart[g + 1];
    for (int p = threadIdx.x; p < PAIRS; p += blockDim.x) {
        float mL = 0.f, mH = 0.f;  // h3 >= 0; empty graph -> 0 (isfinite guard)
        for (int n = s; n < e; ++n) {
            uint v = h3[(size_t)n * PAIRS + p];
            mL = fmaxf(mL, bf2f((ushort)(v & 0xffff)));
            mH = fmaxf(mH, bf2f((ushort)(v >> 16)));
        }
        gb[(size_t)g * PAIRS + p] = (uint)f2bf(mL) | ((uint)f2bf(mH) << 16);
    }
}

extern "C" void kernel_launch(void* const* d_in, const int* in_sizes, int n_in,
                              void* d_out, int out_size, void* d_ws, size_t ws_size,
                              hipStream_t stream) {
    const float* x     = (const float*)d_in[0];
    const int*   eidx  = (const int*)d_in[1];
    const int*   batch = (const int*)d_in[2];
    const float* drug2 = (const float*)d_in[3];
    const float* W1 = (const float*)d_in[4];
    const float* b1 = (const float*)d_in[5];
    const float* W2 = (const float*)d_in[6];
    const float* b2 = (const float*)d_in[7];
    const float* W3 = (const float*)d_in[8];
    const float* b3 = (const float*)d_in[9];
    const float* Wfc = (const float*)d_in[10];
    const float* bfc = (const float*)d_in[11];
    float* out = (float*)d_out;

    const int M = NNODES, E = NEDGES, G = NGRAPHS;
    const int F1 = 78, F2 = 156, F3 = 312, FC = 489;
    const int Kp1 = 96, Np1 = 80;
    const int Kp2 = 96, Np2 = 160;
    const int Kp3 = 160, Np3 = 320;
    const int Kpf = 320, Npf = 496;

    const int* src = eidx;
    const int* dst = eidx + E;
    const int NB = (M + 255) / 256;

    char* ws = (char*)d_ws;
    size_t off = 0;
    auto alloc = [&](size_t bytes) {
        void* p = ws + off;
        off += (bytes + 255) & ~(size_t)255;
        return p;
    };
    ushort* xb   = (ushort*)alloc((size_t)M * Kp1 * 2);
    ushort* h1   = (ushort*)alloc((size_t)M * Np1 * 2);
    ushort* h2   = (ushort*)alloc((size_t)M * Np2 * 2);
    ushort* h3   = (ushort*)alloc((size_t)M * Np3 * 2);
    ushort* agg  = (ushort*)alloc((size_t)M * Kp3 * 2);
    ushort* W1t  = (ushort*)alloc((size_t)Np1 * Kp1 * 2);
    ushort* W2t  = (ushort*)alloc((size_t)Np2 * Kp2 * 2);
    ushort* W3t  = (ushort*)alloc((size_t)Np3 * Kp3 * 2);
    ushort* Wfct = (ushort*)alloc((size_t)Npf * Kpf * 2);
    ushort* gb   = (ushort*)alloc((size_t)G * Kpf * 2);
    float* dis    = (float*)alloc((size_t)M * 4);
    int*   cnt    = (int*)alloc((size_t)M * 4);
    int*   rowptr = (int*)alloc((size_t)(M + 1) * 4);
    int*   cursor = (int*)alloc((size_t)M * 4);
    int*   bsum   = (int*)alloc(1024);
    int*   csr_src = (int*)alloc((size_t)E * 4);
    float* csr_nrm = (float*)alloc((size_t)E * 4);
    int*   gstart  = (int*)alloc((size_t)(G + 1) * 4);

    // ---- CSR build + per-graph bounds
    hipMemsetAsync(cnt, 0, (size_t)M * 4, stream);
    deg_count<<<(E + 255) / 256, 256, 0, stream>>>(dst, cnt, E);
    compute_dis<<<NB, 256, 0, stream>>>(cnt, dis, M);
    block_scan<<<NB, 256, 0, stream>>>(cnt, rowptr, bsum, M);
    scan_bsum<<<1, 256, 0, stream>>>(bsum, NB);
    finalize_rowptr<<<NB, 256, 0, stream>>>(rowptr, cursor, bsum, M, E);
    fill_csr<<<(E + 255) / 256, 256, 0, stream>>>(src, dst, dis, cursor, csr_src, csr_nrm, E);
    graph_bounds<<<NB, 256, 0, stream>>>(batch, gstart, M, G);

    // ---- casts / weight prep
    cast_x<<<(M * Kp1 + 255) / 256, 256, 0, stream>>>(x, xb, M, F1, Kp1);
    prep_w<<<(Np1 * Kp1 + 255) / 256, 256, 0, stream>>>(W1, W1t, F1, F1, Kp1, Np1);
    prep_w<<<(Np2 * Kp2 + 255) / 256, 256, 0, stream>>>(W2, W2t, F1, F2, Kp2, Np2);
    prep_w<<<(Np3 * Kp3 + 255) / 256, 256, 0, stream>>>(W3, W3t, F2, F3, Kp3, Np3);
    prep_w<<<(Npf * Kpf + 255) / 256, 256, 0, stream>>>(Wfc, Wfct, F3, FC, Kpf, Npf);

    const int GG = (M + 3) / 4;
    const int GMX = (M + 63) / 64;

    // ---- layer 1: xb rows = 12 uint4; agg [M][96]; h1 = relu(agg@W1+b1) [M][80]
    gather_ilp<12, 5, 12><<<GG, 256, 0, stream>>>((const uint4*)xb, rowptr, csr_src, csr_nrm, dis, (uint4*)agg);
    gemm_mfma<0><<<dim3(GMX, Np1 / 64 + 1), 256, 0, stream>>>(agg, W1t, h1, nullptr, b1, nullptr, M, Kp1, Np1, F1);

    // ---- layer 2: h1 rows = 10 uint4; agg [M][96]; h2 = relu(agg@W2+b2) [M][160]
    gather_ilp<10, 6, 12><<<GG, 256, 0, stream>>>((const uint4*)h1, rowptr, csr_src, csr_nrm, dis, (uint4*)agg);
    gemm_mfma<0><<<dim3(GMX, Np2 / 64 + 1), 256, 0, stream>>>(agg, W2t, h2, nullptr, b2, nullptr, M, Kp2, Np2, F2);

    // ---- layer 3: h2 rows = 20 uint4; agg [M][160]; h3 = relu(agg@W3+b3) [M][320]
    gather_ilp<20, 3, 20><<<GG, 256, 0, stream>>>((const uint4*)h2, rowptr, csr_src, csr_nrm, dis, (uint4*)agg);
    gemm_mfma<0><<<dim3(GMX, Np3 / 64), 256, 0, stream>>>(agg, W3t, h3, nullptr, b3, nullptr, M, Kp3, Np3, F3);

    // ---- segmented max pool -> gb bf16 [G][320]
    pool_max_seg<<<G, 256, 0, stream>>>((const uint*)h3, gstart, (uint*)gb, Kpf / 2);

    // ---- FC: out = relu(gb@Wfc+bfc)+drug2, f32 [2048][489]
    gemm_mfma<1><<<dim3((G + 63) / 64, (Npf + 63) / 64), 256, 0, stream>>>(gb, Wfct, nullptr, out, bfc, drug2, G, Kpf, Npf, FC);
}

// Round 5
// 291.578 us; speedup vs baseline: 7.3232x; 1.0338x over previous
//
#include <hip/hip_runtime.h>

#define NNODES 50000
#define NEDGES 800000
#define NGRAPHS 2048

typedef __attribute__((ext_vector_type(8))) short bf16x8;
typedef __attribute__((ext_vector_type(4))) float f32x4;

__device__ __forceinline__ float bf2f(ushort u) {
    return __uint_as_float(((uint)u) << 16);
}
__device__ __forceinline__ ushort f2bf(float f) {
    uint u = __float_as_uint(f);
    return (ushort)((u + 0x7fff + ((u >> 16) & 1)) >> 16);  // RNE
}

// ---------------- degree ----------------
__global__ void deg_count(const int* __restrict__ dst, int* __restrict__ cnt, int E) {
    int e = blockIdx.x * blockDim.x + threadIdx.x;
    if (e < E) atomicAdd(&cnt[dst[e]], 1);
}

// ---------------- CSR build ----------------
__global__ void block_scan(const int* __restrict__ cnt, int* __restrict__ lp,
                           int* __restrict__ bsum, int M) {
    __shared__ int s[256];
    int t = threadIdx.x;
    int n = blockIdx.x * 256 + t;
    int v = (n < M) ? cnt[n] : 0;
    s[t] = v;
    __syncthreads();
    #pragma unroll
    for (int off = 1; off < 256; off <<= 1) {
        int u = (t >= off) ? s[t - off] : 0;
        __syncthreads();
        s[t] += u;
        __syncthreads();
    }
    if (n < M) lp[n] = s[t] - v;
    if (t == 255) bsum[blockIdx.x] = s[255];
}

__global__ void scan_bsum(int* __restrict__ bsum, int NB) {
    __shared__ int s[256];
    int t = threadIdx.x;
    int v = (t < NB) ? bsum[t] : 0;
    s[t] = v;
    __syncthreads();
    #pragma unroll
    for (int off = 1; off < 256; off <<= 1) {
        int u = (t >= off) ? s[t - off] : 0;
        __syncthreads();
        s[t] += u;
        __syncthreads();
    }
    if (t < NB) bsum[t] = s[t] - v;
}

// rowptr finalize + cursor init + dis = rsqrt(deg+1) fused
__global__ void finalize_rowptr(int* __restrict__ rowptr, int* __restrict__ cursor,
                                const int* __restrict__ bsum, const int* __restrict__ cnt,
                                float* __restrict__ dis, int M, int E) {
    int n = blockIdx.x * blockDim.x + threadIdx.x;
    if (n < M) {
        int v = rowptr[n] + bsum[n >> 8];
        rowptr[n] = v;
        cursor[n] = v;
        dis[n] = rsqrtf((float)(cnt[n] + 1));
    }
    if (n == 0) rowptr[M] = E;
}

// packed (src, norm) single 8B store per edge
__global__ void fill_csr(const int* __restrict__ src, const int* __restrict__ dst,
                         const float* __restrict__ dis, int* __restrict__ cursor,
                         int2* __restrict__ csr, int E) {
    int e = blockIdx.x * blockDim.x + threadIdx.x;
    if (e >= E) return;
    int s = src[e], d = dst[e];
    int pos = atomicAdd(&cursor[d], 1);
    csr[pos] = make_int2(s, __float_as_int(dis[s] * dis[d]));
}

// ---------------- input cast / weight prep ----------------
__global__ void cast_x(const float* __restrict__ x, ushort* __restrict__ xb,
                       int M, int K, int Kp) {
    int idx = blockIdx.x * blockDim.x + threadIdx.x;
    if (idx >= M * Kp) return;
    int n = idx / Kp, k = idx % Kp;
    xb[idx] = (k < K) ? f2bf(x[(size_t)n * K + k]) : (ushort)0;
}

// Wt[n][k] = W[k][n], bf16, zero-padded to [Np][Kp]
__global__ void prep_w(const float* __restrict__ W, ushort* __restrict__ Wt,
                       int K, int N, int Kp, int Np) {
    int idx = blockIdx.x * blockDim.x + threadIdx.x;
    if (idx >= Kp * Np) return;
    int n = idx / Kp, k = idx % Kp;
    Wt[idx] = (k < K && n < N) ? f2bf(W[(size_t)k * N + n]) : (ushort)0;
}

// ---------------- ILP gather: lanes = (sub-edge, uint4-chunk), 4x unroll ----------------
__device__ __forceinline__ void acc8(float* acc, uint4 v, float nm) {
    acc[0] += bf2f((ushort)(v.x & 0xffff)) * nm;
    acc[1] += bf2f((ushort)(v.x >> 16)) * nm;
    acc[2] += bf2f((ushort)(v.y & 0xffff)) * nm;
    acc[3] += bf2f((ushort)(v.y >> 16)) * nm;
    acc[4] += bf2f((ushort)(v.z & 0xffff)) * nm;
    acc[5] += bf2f((ushort)(v.z >> 16)) * nm;
    acc[6] += bf2f((ushort)(v.w & 0xffff)) * nm;
    acc[7] += bf2f((ushort)(v.w >> 16)) * nm;
}

template <int CH, int SUB, int CHOUT>
__global__ __launch_bounds__(256) void gather_ilp(const uint4* __restrict__ h,
                                                  const int* __restrict__ rowptr,
                                                  const int2* __restrict__ csr,
                                                  const float* __restrict__ dis,
                                                  uint4* __restrict__ agg) {
    int node = blockIdx.x * 4 + (threadIdx.x >> 6);
    if (node >= NNODES) return;
    int lane = threadIdx.x & 63;
    int sub = lane / CH;
    int ch = lane % CH;
    bool active = sub < SUB;

    float acc[8] = {};
    int beg = rowptr[node], end = rowptr[node + 1];
    for (int i = beg; i < end; i += 4 * SUB) {
        // phase 1: edge records (4 independent 8B loads)
        int2 ev[4];
        int vld[4];
        #pragma unroll
        for (int u = 0; u < 4; ++u) {
            int e = i + u * SUB + sub;
            vld[u] = active && (e < end);
            ev[u] = vld[u] ? csr[e] : make_int2(0, 0);
        }
        // phase 2: rows (4 independent 16B loads)
        uint4 av[4];
        #pragma unroll
        for (int u = 0; u < 4; ++u)
            av[u] = vld[u] ? h[(size_t)ev[u].x * CH + ch] : make_uint4(0, 0, 0, 0);
        // phase 3: accumulate (nm = 0 for invalid slots)
        #pragma unroll
        for (int u = 0; u < 4; ++u)
            acc8(acc, av[u], __int_as_float(ev[u].y));
    }

    // reduce partials across sub groups (read-only sources -> no contamination)
    float tot[8];
    #pragma unroll
    for (int j = 0; j < 8; ++j) tot[j] = acc[j];
    #pragma unroll
    for (int sb = 1; sb < SUB; ++sb) {
        int srcLane = ch + sb * CH;
        #pragma unroll
        for (int j = 0; j < 8; ++j) tot[j] += __shfl(acc[j], srcLane);
    }

    if (lane < CHOUT) {
        uint4 o = make_uint4(0, 0, 0, 0);
        if (lane < CH) {
            float di = dis[node];
            float d2 = di * di;
            uint4 hs = h[(size_t)node * CH + lane];
            tot[0] += bf2f((ushort)(hs.x & 0xffff)) * d2;
            tot[1] += bf2f((ushort)(hs.x >> 16)) * d2;
            tot[2] += bf2f((ushort)(hs.y & 0xffff)) * d2;
            tot[3] += bf2f((ushort)(hs.y >> 16)) * d2;
            tot[4] += bf2f((ushort)(hs.z & 0xffff)) * d2;
            tot[5] += bf2f((ushort)(hs.z >> 16)) * d2;
            tot[6] += bf2f((ushort)(hs.w & 0xffff)) * d2;
            tot[7] += bf2f((ushort)(hs.w >> 16)) * d2;
            o.x = (uint)f2bf(tot[0]) | ((uint)f2bf(tot[1]) << 16);
            o.y = (uint)f2bf(tot[2]) | ((uint)f2bf(tot[3]) << 16);
            o.z = (uint)f2bf(tot[4]) | ((uint)f2bf(tot[5]) << 16);
            o.w = (uint)f2bf(tot[6]) | ((uint)f2bf(tot[7]) << 16);
        }
        agg[(size_t)node * CHOUT + lane] = o;
    }
}

// ---------------- MFMA bf16 GEMM: C = epi(A[M][Kp] @ Wt[Np][Kp]^T) ----------------
template <int EPI>
__global__ __launch_bounds__(256) void gemm_mfma(const ushort* __restrict__ A,
                                                 const ushort* __restrict__ Bt,
                                                 ushort* __restrict__ Cb,
                                                 float* __restrict__ Cf,
                                                 const float* __restrict__ bias,
                                                 const float* __restrict__ addend,
                                                 int M, int Kp, int Np, int Nreal) {
    __shared__ ushort Asl[64 * 32];
    __shared__ ushort Bsl[64 * 32];
    const int tid = threadIdx.x;
    const int lane = tid & 63;
    const int wid = tid >> 6;
    const int wm = (wid >> 1) * 32, wn = (wid & 1) * 32;
    const int bm = blockIdx.x * 64, bn = blockIdx.y * 64;

    const int sr = tid >> 2;
    const int sc = tid & 3;
    const int swz = sc ^ ((sr >> 1) & 3);
    const int lc = lane >> 4;

    f32x4 acc[2][2] = {};
    for (int k0 = 0; k0 < Kp; k0 += 32) {
        bf16x8 av = {};
        int gr = bm + sr;
        if (gr < M) av = *(const bf16x8*)&A[(size_t)gr * Kp + k0 + sc * 8];
        *(bf16x8*)&Asl[sr * 32 + swz * 8] = av;
        bf16x8 bv = {};
        int gn = bn + sr;
        if (gn < Np) bv = *(const bf16x8*)&Bt[(size_t)gn * Kp + k0 + sc * 8];
        *(bf16x8*)&Bsl[sr * 32 + swz * 8] = bv;
        __syncthreads();
        bf16x8 af[2], bfr[2];
        #pragma unroll
        for (int m = 0; m < 2; ++m) {
            int r = wm + m * 16 + (lane & 15);
            int pc = lc ^ ((r >> 1) & 3);
            af[m] = *(const bf16x8*)&Asl[r * 32 + pc * 8];
        }
        #pragma unroll
        for (int n = 0; n < 2; ++n) {
            int r = wn + n * 16 + (lane & 15);
            int pc = lc ^ ((r >> 1) & 3);
            bfr[n] = *(const bf16x8*)&Bsl[r * 32 + pc * 8];
        }
        #pragma unroll
        for (int m = 0; m < 2; ++m)
            #pragma unroll
            for (int n = 0; n < 2; ++n)
                acc[m][n] = __builtin_amdgcn_mfma_f32_16x16x32_bf16(af[m], bfr[n], acc[m][n], 0, 0, 0);
        __syncthreads();
    }
    #pragma unroll
    for (int m = 0; m < 2; ++m) {
        #pragma unroll
        for (int n = 0; n < 2; ++n) {
            int gc = bn + wn + n * 16 + (lane & 15);
            #pragma unroll
            for (int j = 0; j < 4; ++j) {
                int gr = bm + wm + m * 16 + (lane >> 4) * 4 + j;
                if (gr >= M) continue;
                float v = acc[m][n][j];
                if (EPI == 0) {
                    if (gc < Np) {
                        float o = (gc < Nreal) ? fmaxf(v + bias[gc], 0.f) : 0.f;
                        Cb[(size_t)gr * Np + gc] = f2bf(o);
                    }
                } else {
                    if (gc < Nreal) {
                        float o = fmaxf(v + bias[gc], 0.f) + addend[(size_t)gr * Nreal + gc];
                        Cf[(size_t)gr * Nreal + gc] = o;
                    }
                }
            }
        }
    }
}

// ---------------- per-graph segment bounds (batch is sorted) ----------------
__global__ void graph_bounds(const int* __restrict__ batch, int* __restrict__ gstart,
                             int M, int G) {
    int n = blockIdx.x * blockDim.x + threadIdx.x;
    if (n >= M) return;
    int b = batch[n];
    int bp = (n == 0) ? -1 : batch[n - 1];
    for (int gg = bp + 1; gg <= b; ++gg) gstart[gg] = n;
    if (n == M - 1) {
        for (int gg = b + 1; gg <= G; ++gg) gstart[gg] = M;
    }
}

// ---------------- segmented max pool: block per graph, bf16 out ----------------
__global__ void pool_max_seg(const uint* __restrict__ h3, const int* __restrict__ gstart,
                             uint* __restrict__ gb, int PAIRS) {
    int g = blockIdx.x;
    int s = gstart[g], e = gstart[g + 1];
    for (int p = threadIdx.x; p < PAIRS; p += blockDim.x) {
        float mL = 0.f, mH = 0.f;  // h3 >= 0; empty graph -> 0 (isfinite guard)
        for (int n = s; n < e; ++n) {
            uint v = h3[(size_t)n * PAIRS + p];
            mL = fmaxf(mL, bf2f((ushort)(v & 0xffff)));
            mH = fmaxf(mH, bf2f((ushort)(v >> 16)));
        }
        gb[(size_t)g * PAIRS + p] = (uint)f2bf(mL) | ((uint)f2bf(mH) << 16);
    }
}

extern "C" void kernel_launch(void* const* d_in, const int* in_sizes, int n_in,
                              void* d_out, int out_size, void* d_ws, size_t ws_size,
                              hipStream_t stream) {
    const float* x     = (const float*)d_in[0];
    const int*   eidx  = (const int*)d_in[1];
    const int*   batch = (const int*)d_in[2];
    const float* drug2 = (const float*)d_in[3];
    const float* W1 = (const float*)d_in[4];
    const float* b1 = (const float*)d_in[5];
    const float* W2 = (const float*)d_in[6];
    const float* b2 = (const float*)d_in[7];
    const float* W3 = (const float*)d_in[8];
    const float* b3 = (const float*)d_in[9];
    const float* Wfc = (const float*)d_in[10];
    const float* bfc = (const float*)d_in[11];
    float* out = (float*)d_out;

    const int M = NNODES, E = NEDGES, G = NGRAPHS;
    const int F1 = 78, F2 = 156, F3 = 312, FC = 489;
    const int Kp1 = 96, Np1 = 80;
    const int Kp2 = 96, Np2 = 160;
    const int Kp3 = 160, Np3 = 320;
    const int Kpf = 320, Npf = 496;

    const int* src = eidx;
    const int* dst = eidx + E;
    const int NB = (M + 255) / 256;

    char* ws = (char*)d_ws;
    size_t off = 0;
    auto alloc = [&](size_t bytes) {
        void* p = ws + off;
        off += (bytes + 255) & ~(size_t)255;
        return p;
    };
    ushort* xb   = (ushort*)alloc((size_t)M * Kp1 * 2);
    ushort* h1   = (ushort*)alloc((size_t)M * Np1 * 2);
    ushort* h2   = (ushort*)alloc((size_t)M * Np2 * 2);
    ushort* h3   = (ushort*)alloc((size_t)M * Np3 * 2);
    ushort* agg  = (ushort*)alloc((size_t)M * Kp3 * 2);
    ushort* W1t  = (ushort*)alloc((size_t)Np1 * Kp1 * 2);
    ushort* W2t  = (ushort*)alloc((size_t)Np2 * Kp2 * 2);
    ushort* W3t  = (ushort*)alloc((size_t)Np3 * Kp3 * 2);
    ushort* Wfct = (ushort*)alloc((size_t)Npf * Kpf * 2);
    ushort* gb   = (ushort*)alloc((size_t)G * Kpf * 2);
    float* dis    = (float*)alloc((size_t)M * 4);
    int*   cnt    = (int*)alloc((size_t)M * 4);
    int*   rowptr = (int*)alloc((size_t)(M + 1) * 4);
    int*   cursor = (int*)alloc((size_t)M * 4);
    int*   bsum   = (int*)alloc(1024);
    int2*  csr    = (int2*)alloc((size_t)E * 8);
    int*   gstart  = (int*)alloc((size_t)(G + 1) * 4);

    // ---- CSR build + per-graph bounds
    hipMemsetAsync(cnt, 0, (size_t)M * 4, stream);
    deg_count<<<(E + 255) / 256, 256, 0, stream>>>(dst, cnt, E);
    block_scan<<<NB, 256, 0, stream>>>(cnt, rowptr, bsum, M);
    scan_bsum<<<1, 256, 0, stream>>>(bsum, NB);
    finalize_rowptr<<<NB, 256, 0, stream>>>(rowptr, cursor, bsum, cnt, dis, M, E);
    fill_csr<<<(E + 255) / 256, 256, 0, stream>>>(src, dst, dis, cursor, csr, E);
    graph_bounds<<<NB, 256, 0, stream>>>(batch, gstart, M, G);

    // ---- casts / weight prep
    cast_x<<<(M * Kp1 + 255) / 256, 256, 0, stream>>>(x, xb, M, F1, Kp1);
    prep_w<<<(Np1 * Kp1 + 255) / 256, 256, 0, stream>>>(W1, W1t, F1, F1, Kp1, Np1);
    prep_w<<<(Np2 * Kp2 + 255) / 256, 256, 0, stream>>>(W2, W2t, F1, F2, Kp2, Np2);
    prep_w<<<(Np3 * Kp3 + 255) / 256, 256, 0, stream>>>(W3, W3t, F2, F3, Kp3, Np3);
    prep_w<<<(Npf * Kpf + 255) / 256, 256, 0, stream>>>(Wfc, Wfct, F3, FC, Kpf, Npf);

    const int GG = (M + 3) / 4;
    const int GMX = (M + 63) / 64;

    // ---- layer 1: xb rows = 12 uint4; agg [M][96]; h1 = relu(agg@W1+b1) [M][80]
    gather_ilp<12, 5, 12><<<GG, 256, 0, stream>>>((const uint4*)xb, rowptr, csr, dis, (uint4*)agg);
    gemm_mfma<0><<<dim3(GMX, Np1 / 64 + 1), 256, 0, stream>>>(agg, W1t, h1, nullptr, b1, nullptr, M, Kp1, Np1, F1);

    // ---- layer 2: h1 rows = 10 uint4; agg [M][96]; h2 = relu(agg@W2+b2) [M][160]
    gather_ilp<10, 6, 12><<<GG, 256, 0, stream>>>((const uint4*)h1, rowptr, csr, dis, (uint4*)agg);
    gemm_mfma<0><<<dim3(GMX, Np2 / 64 + 1), 256, 0, stream>>>(agg, W2t, h2, nullptr, b2, nullptr, M, Kp2, Np2, F2);

    // ---- layer 3: h2 rows = 20 uint4; agg [M][160]; h3 = relu(agg@W3+b3) [M][320]
    gather_ilp<20, 3, 20><<<GG, 256, 0, stream>>>((const uint4*)h2, rowptr, csr, dis, (uint4*)agg);
    gemm_mfma<0><<<dim3(GMX, Np3 / 64), 256, 0, stream>>>(agg, W3t, h3, nullptr, b3, nullptr, M, Kp3, Np3, F3);

    // ---- segmented max pool -> gb bf16 [G][320]
    pool_max_seg<<<G, 256, 0, stream>>>((const uint*)h3, gstart, (uint*)gb, Kpf / 2);

    // ---- FC: out = relu(gb@Wfc+bfc)+drug2, f32 [2048][489]
    gemm_mfma<1><<<dim3((G + 63) / 64, (Npf + 63) / 64), 256, 0, stream>>>(gb, Wfct, nullptr, out, bfc, drug2, G, Kpf, Npf, FC);
}